// Round 1
// baseline (232.229 us; speedup 1.0000x reference)
//
#include <hip/hip_runtime.h>
#include <math.h>

// Problem dims (from setup_inputs): B=4, C=8, H=W=256
#define B_DIM 4
#define C_DIM 8
#define H_DIM 256
#define W_DIM 256
#define HW 65536          // H*W
#define NPIX 262144       // B*H*W

// Workspace layout:
// [0   .. 32)    double acc[4]: 0=ce_sum, 1=inter_sum, 2=probs_sum(valid_d), 3=bound_num
// [64  .. 204)   int icnt[35]: 0=valid_d_cnt, 1=valid_b_cnt, 2=onehot_cnt, 3+bc = seed cnt per (b,c)
// [1024 .. 1024+1MB)  float lse[NPIX]
// [2MB .. 18MB)  float g2[64][HW]  (job = bc*2 + pol; pol0: seed=cm, pol1: seed=~cm)

__device__ __forceinline__ float block_reduce_sum(float v, float* red, int tid) {
    red[tid] = v;
    __syncthreads();
    for (int s = 128; s > 0; s >>= 1) {
        if (tid < s) red[tid] += red[tid + s];
        __syncthreads();
    }
    float r = red[0];
    __syncthreads();
    return r;
}

// Kernel A: per-pixel softmax; CE / Dice partial sums; counts; lse map.
__global__ void k_softmax_stats(const float* __restrict__ x,
                                const int* __restrict__ tgt,
                                float* __restrict__ lse_out,
                                double* __restrict__ acc,
                                int* __restrict__ icnt) {
    int p = blockIdx.x * blockDim.x + threadIdx.x;   // pixel index [0, NPIX)
    int tid = threadIdx.x;
    int b = p >> 16;             // HW = 65536
    const float* base = x + (size_t)b * C_DIM * HW + (p & (HW - 1));

    float v[C_DIM];
    float m = -1e30f;
#pragma unroll
    for (int c = 0; c < C_DIM; ++c) {
        v[c] = base[(size_t)c * HW];
        m = fmaxf(m, v[c]);
    }
    float s = 0.f;
#pragma unroll
    for (int c = 0; c < C_DIM; ++c) s += expf(v[c] - m);
    float lse = m + logf(s);
    lse_out[p] = lse;

    int t = tgt[p];
    bool valid_d = (t >= 0);
    bool valid_b = (t != -100) && (t >= 0) && (t < C_DIM);
    int tc = (t >= 0 && t < C_DIM) ? t : 0;

    float ce = lse - v[tc];                                   // -logp_target
    float psum = 0.f;
#pragma unroll
    for (int c = 0; c < C_DIM; ++c) psum += expf(v[c] - lse); // sum of probs
    float inter = (valid_d && t < C_DIM) ? expf(v[tc] - lse) : 0.f;
    float psum_m = valid_d ? psum : 0.f;

    __shared__ float red[256];
    __shared__ int hist[C_DIM];
    __shared__ int scnt[3];
    if (tid < C_DIM) hist[tid] = 0;
    if (tid < 3) scnt[tid] = 0;
    __syncthreads();
    if (valid_d) atomicAdd(&scnt[0], 1);
    if (valid_b) { atomicAdd(&scnt[1], 1); atomicAdd(&hist[t], 1); }
    if (valid_d && t < C_DIM) atomicAdd(&scnt[2], 1);
    __syncthreads();

    float s_ce    = block_reduce_sum(ce, red, tid);
    float s_inter = block_reduce_sum(inter, red, tid);
    float s_psum  = block_reduce_sum(psum_m, red, tid);

    if (tid == 0) {
        atomicAdd(&acc[0], (double)s_ce);
        atomicAdd(&acc[1], (double)s_inter);
        atomicAdd(&acc[2], (double)s_psum);
        atomicAdd(&icnt[0], scnt[0]);
        atomicAdd(&icnt[1], scnt[1]);
        atomicAdd(&icnt[2], scnt[2]);
    }
    if (tid < C_DIM) atomicAdd(&icnt[3 + b * C_DIM + tid], hist[tid]);
}

// Kernel B: horizontal EDT pass. One thread per (job, row). Exact integer scan,
// matches reference: d1 = min(dl, dr, H+W=512), g2 = d1^2 (exact in f32).
__global__ void k_edt_rows(const int* __restrict__ tgt, float* __restrict__ g2) {
    int gid = blockIdx.x * blockDim.x + threadIdx.x;  // [0, 64*256)
    int j = gid >> 8;          // job
    int y = gid & 255;
    int pol = j & 1;
    int bc = j >> 1;
    int b = bc >> 3, c = bc & 7;

    const int* row = tgt + (size_t)b * HW + y * W_DIM;
    float* grow = g2 + (size_t)j * HW + y * W_DIM;

    // left pass: store dl
    int last = -1000000;
    for (int i = 0; i < W_DIM; ++i) {
        int t = row[i];
        bool valid = (t != -100) && (t >= 0) && (t < C_DIM);
        bool cm = valid && (t == c);
        bool seed = pol ? !cm : cm;
        if (seed) last = i;
        grow[i] = (float)(i - last);   // >= 512 when no seed to the left
    }
    // right pass: combine, cap, square
    int lastr = 2000000;
    for (int i = W_DIM - 1; i >= 0; --i) {
        int t = row[i];
        bool valid = (t != -100) && (t >= 0) && (t < C_DIM);
        bool cm = valid && (t == c);
        bool seed = pol ? !cm : cm;
        if (seed) lastr = i;
        int dr = lastr - i;
        int dl = (int)grow[i];
        int d1 = min(min(dl, dr), 512);
        grow[i] = (float)(d1 * d1);
    }
}

// Kernel C: vertical lower-envelope (brute force, exact), signed distance,
// fused with boundary-loss numerator reduction. One block per (bc, column).
__global__ void k_edt_cols_bound(const float* __restrict__ g2,
                                 const float* __restrict__ x,
                                 const float* __restrict__ lse,
                                 const int* __restrict__ tgt,
                                 const int* __restrict__ icnt,
                                 double* __restrict__ acc) {
    int bc = blockIdx.x >> 8;          // [0, 32)
    int xcol = blockIdx.x & 255;
    int y = threadIdx.x;
    int b = bc >> 3, c = bc & 7;

    __shared__ float g0[H_DIM];
    __shared__ float g1[H_DIM];
    __shared__ float red[256];

    size_t j0 = (size_t)(bc * 2) * HW;
    g0[y] = g2[j0 + (size_t)y * W_DIM + xcol];
    g1[y] = g2[j0 + HW + (size_t)y * W_DIM + xcol];
    __syncthreads();

    float m0 = 1e30f, m1 = 1e30f;
    for (int yp = 0; yp < H_DIM; ++yp) {
        int d = y - yp;
        float dy2 = (float)(d * d);
        m0 = fminf(m0, dy2 + g0[yp]);
        m1 = fminf(m1, dy2 + g1[yp]);
    }
    float dout = sqrtf(m0);
    float din  = sqrtf(m1);

    int cnt = icnt[3 + bc];
    bool has_pos = cnt > 0;
    bool has_neg = cnt < HW;
    float sgn = has_pos ? (has_neg ? (dout - din) : dout) : 0.f;

    int t = tgt[(size_t)b * HW + (size_t)y * W_DIM + xcol];
    bool valid_b = (t != -100) && (t >= 0) && (t < C_DIM);
    float dmap = valid_b ? sgn : 0.f;

    size_t pix = (size_t)b * HW + (size_t)y * W_DIM + xcol;
    float prob = expf(x[((size_t)b * C_DIM + c) * HW + (size_t)y * W_DIM + xcol] - lse[pix]);
    float contrib = prob * dmap;   // vbf multiply == valid_b, already applied

    float s = block_reduce_sum(contrib, red, y);
    if (y == 0) atomicAdd(&acc[3], (double)s);
}

// Kernel D: combine the scalars.
__global__ void k_finalize(const double* __restrict__ acc,
                           const int* __restrict__ icnt,
                           float* __restrict__ out) {
    double ce = acc[0] / (double)NPIX;
    double inter = acc[1];
    double card = acc[2] + (double)icnt[2];
    double dice = 1.0 - (2.0 * inter + 1e-6) / (card + 1e-6);
    double dice_total = 0.1 * ce + 0.9 * dice;
    double bound = acc[3] / ((double)icnt[1] + 1e-8);
    out[0] = (float)(0.1 * ce + (1.0 - 0.1 - 0.1) * dice_total + 0.1 * bound);
}

extern "C" void kernel_launch(void* const* d_in, const int* in_sizes, int n_in,
                              void* d_out, int out_size, void* d_ws, size_t ws_size,
                              hipStream_t stream) {
    const float* x = (const float*)d_in[0];
    const int* tgt = (const int*)d_in[1];
    float* out = (float*)d_out;

    char* ws = (char*)d_ws;
    double* acc = (double*)ws;
    int* icnt = (int*)(ws + 64);
    float* lse = (float*)(ws + 1024);
    float* g2 = (float*)(ws + (size_t)(2u << 20));

    hipMemsetAsync(ws, 0, 512, stream);

    k_softmax_stats<<<NPIX / 256, 256, 0, stream>>>(x, tgt, lse, acc, icnt);
    k_edt_rows<<<64, 256, 0, stream>>>(tgt, g2);
    k_edt_cols_bound<<<32 * 256, 256, 0, stream>>>(g2, x, lse, tgt, icnt, acc);
    k_finalize<<<1, 1, 0, stream>>>(acc, icnt, out);
}

// Round 2
// 91.812 us; speedup vs baseline: 2.5294x; 2.5294x over previous
//
#include <hip/hip_runtime.h>
#include <math.h>

// Dims: B=4, C=8, H=W=256
#define B_DIM 4
#define C_DIM 8
#define H_DIM 256
#define W_DIM 256
#define HW 65536
#define NPIX 262144

// ws layout:
// [0, 512)        int icnt[]: [1]=valid_b count, [3+bc]=seed count per (b,c)   (memset 0 each call)
// [4096, 8192)    float pce[1024]
// [8192, 12288)   float pinter[1024]
// [12288,16384)   float ppsum[1024]
// [16384,18432)   float pbound[512]
// [32768, +1MB)   float lse[NPIX]
// [2MB, +16MB)    float g2[64][HW]   job j = bc*2+pol; pol0 seed=cm, pol1 seed=~cm

__device__ __forceinline__ float wave_reduce_f(float v) {
#pragma unroll
    for (int off = 32; off; off >>= 1) v += __shfl_xor(v, off, 64);
    return v;
}

// ---------------- Kernel A: softmax stats (lse map, CE/Dice partials, counts) ----------------
__global__ void k_softmax_stats(const float* __restrict__ x,
                                const int* __restrict__ tgt,
                                float* __restrict__ lse_out,
                                int* __restrict__ icnt,
                                float* __restrict__ pce,
                                float* __restrict__ pinter,
                                float* __restrict__ ppsum) {
    int bi = blockIdx.x;                 // 1024 blocks; each block = 256 consecutive pixels, one image
    int tid = threadIdx.x;
    int p = bi * 256 + tid;
    int lane = tid & 63, wid = tid >> 6;
    int b = p >> 16;
    const float* base = x + (size_t)b * C_DIM * HW + (p & (HW - 1));

    float v[C_DIM];
    float m = -1e30f;
#pragma unroll
    for (int c = 0; c < C_DIM; ++c) { v[c] = base[(size_t)c * HW]; m = fmaxf(m, v[c]); }
    float s = 0.f;
#pragma unroll
    for (int c = 0; c < C_DIM; ++c) s += expf(v[c] - m);
    float lse = m + logf(s);
    lse_out[p] = lse;

    int t = tgt[p];
    bool valid_d = (t >= 0);
    bool valid_b = valid_d && (t < C_DIM);   // (t!=-100) subsumed by t>=0
    int tc = valid_b ? t : 0;
    float vt = v[0];
#pragma unroll
    for (int c = 1; c < C_DIM; ++c) vt = (tc == c) ? v[c] : vt;

    float ce = lse - vt;
    float psum = 0.f;
#pragma unroll
    for (int c = 0; c < C_DIM; ++c) psum += expf(v[c] - lse);
    float inter = valid_b ? expf(vt - lse) : 0.f;
    float psum_m = valid_d ? psum : 0.f;

    // float partial sums: shfl within wave, LDS across waves
    __shared__ float ws_ce[4], ws_in[4], ws_ps[4];
    __shared__ int cnt_b[4];
    __shared__ int hist[C_DIM];
    if (tid < C_DIM) hist[tid] = 0;
    __syncthreads();

    float r_ce = wave_reduce_f(ce);
    float r_in = wave_reduce_f(inter);
    float r_ps = wave_reduce_f(psum_m);
    unsigned long long mb = __ballot(valid_b);
#pragma unroll
    for (int c = 0; c < C_DIM; ++c) {
        unsigned long long mc = __ballot(valid_b && (t == c));
        if (lane == 0 && mc) atomicAdd(&hist[c], __popcll(mc));
    }
    if (lane == 0) {
        ws_ce[wid] = r_ce; ws_in[wid] = r_in; ws_ps[wid] = r_ps;
        cnt_b[wid] = __popcll(mb);
    }
    __syncthreads();
    if (tid == 0) {
        pce[bi]    = (ws_ce[0] + ws_ce[1]) + (ws_ce[2] + ws_ce[3]);
        pinter[bi] = (ws_in[0] + ws_in[1]) + (ws_in[2] + ws_in[3]);
        ppsum[bi]  = (ws_ps[0] + ws_ps[1]) + (ws_ps[2] + ws_ps[3]);
        atomicAdd(&icnt[1], (cnt_b[0] + cnt_b[1]) + (cnt_b[2] + cnt_b[3]));
    }
    if (tid < C_DIM && hist[tid] > 0) atomicAdd(&icnt[3 + b * C_DIM + tid], hist[tid]);
}

// ---------------- Kernel B: horizontal EDT via ballot bit-tricks ----------------
__global__ void k_edt_rows(const int* __restrict__ tgt, float* __restrict__ g2) {
    int bi = blockIdx.x;                 // [0,1024): b*256 + y
    int b = bi >> 8, y = bi & 255;
    int i = threadIdx.x;                 // pixel column
    int lane = i & 63, wid = i >> 6;

    int t = tgt[(size_t)b * HW + (size_t)y * W_DIM + i];
    bool valid = (t >= 0) && (t < C_DIM);

    __shared__ unsigned long long wmask[C_DIM][4];
#pragma unroll
    for (int c = 0; c < C_DIM; ++c) {
        unsigned long long mc = __ballot(valid && (t == c));
        if (lane == 0) wmask[c][wid] = mc;
    }
    __syncthreads();

    unsigned long long lm_le = (~0ull) >> (63 - lane);
    unsigned long long lm_ge = (~0ull) << lane;

#pragma unroll 1
    for (int c = 0; c < C_DIM; ++c) {
        unsigned long long m0 = wmask[c][wid];
#pragma unroll
        for (int pol = 0; pol < 2; ++pol) {
            unsigned long long mk = pol ? ~m0 : m0;
            unsigned long long mle = mk & lm_le;
            unsigned long long mge = mk & lm_ge;
            int last, next;
            if (mle) last = (wid << 6) + 63 - __builtin_clzll(mle);
            else {
                last = -1000;
                for (int w = wid - 1; w >= 0; --w) {
                    unsigned long long mw = pol ? ~wmask[c][w] : wmask[c][w];
                    if (mw) { last = (w << 6) + 63 - __builtin_clzll(mw); break; }
                }
            }
            if (mge) next = (wid << 6) + __builtin_ctzll(mge);
            else {
                next = 100000;
                for (int w = wid + 1; w < 4; ++w) {
                    unsigned long long mw = pol ? ~wmask[c][w] : wmask[c][w];
                    if (mw) { next = (w << 6) + __builtin_ctzll(mw); break; }
                }
            }
            int d1 = min(min(i - last, next - i), 512);
            int j = ((b * C_DIM + c) << 1) + pol;
            g2[(size_t)j * HW + (size_t)y * W_DIM + i] = (float)(d1 * d1);
        }
    }
}

// ---------------- Kernel C: vertical lower-envelope (register-tiled min-plus) + boundary sum ----
__global__ void __launch_bounds__(256) k_edt_cols_bound(
    const float* __restrict__ g2, const float* __restrict__ x,
    const float* __restrict__ lse, const int* __restrict__ tgt,
    const int* __restrict__ icnt, float* __restrict__ pbound) {
    int blk = blockIdx.x;            // [0, 512)
    int bc = blk >> 4;               // [0, 32)
    int xt = blk & 15;               // x-tile of 16 columns
    int b = bc >> 3, c = bc & 7;
    int tid = threadIdx.x;
    int ty = tid >> 2;               // 0..63  -> y = ty*4 .. ty*4+3
    int tx = tid & 3;                // 0..3   -> x = xt*16 + tx*4 .. +3
    int lane = tid & 63, wid = tid >> 6;

    __shared__ float h0[H_DIM][16];
    __shared__ float h1[H_DIM][16];

    // load g2 columns into LDS with +yp^2 folded in
    {
        size_t j0 = (size_t)(bc << 1) * HW;
        int chunk = tid & 3;
        int ypb = tid >> 2;
#pragma unroll
        for (int pass = 0; pass < 4; ++pass) {
            int yp = ypb + (pass << 6);
            float ypf = (float)yp;
            float yp2 = ypf * ypf;
            size_t off = (size_t)yp * W_DIM + (xt << 4) + (chunk << 2);
            float4 v0 = *(const float4*)(g2 + j0 + off);
            float4 v1 = *(const float4*)(g2 + j0 + HW + off);
            *(float4*)&h0[yp][chunk << 2] = make_float4(v0.x + yp2, v0.y + yp2, v0.z + yp2, v0.w + yp2);
            *(float4*)&h1[yp][chunk << 2] = make_float4(v1.x + yp2, v1.y + yp2, v1.z + yp2, v1.w + yp2);
        }
    }
    __syncthreads();

    int ybase = ty << 2;
    float f0 = -2.0f * (float)(ybase + 0);
    float f1 = -2.0f * (float)(ybase + 1);
    float f2 = -2.0f * (float)(ybase + 2);
    float f3 = -2.0f * (float)(ybase + 3);

    float m0[4][4], m1[4][4];
#pragma unroll
    for (int iy = 0; iy < 4; ++iy)
#pragma unroll
        for (int j = 0; j < 4; ++j) { m0[iy][j] = 1e30f; m1[iy][j] = 1e30f; }

    // min-plus: m[iy][j] = min_yp ( f_iy*yp + h[yp][j] );   exact (all ints < 2^24)
    for (int yp = 0; yp < H_DIM; yp += 2) {
        float ya = (float)yp, yb = (float)(yp + 1);
        float4 a0 = *(float4*)&h0[yp][tx << 2];
        float4 b0 = *(float4*)&h0[yp + 1][tx << 2];
        float4 a1 = *(float4*)&h1[yp][tx << 2];
        float4 b1 = *(float4*)&h1[yp + 1][tx << 2];
#pragma unroll
        for (int iy = 0; iy < 4; ++iy) {
            float fi = (iy == 0) ? f0 : (iy == 1) ? f1 : (iy == 2) ? f2 : f3;
            m0[iy][0] = fminf(m0[iy][0], fminf(fmaf(fi, ya, a0.x), fmaf(fi, yb, b0.x)));
            m0[iy][1] = fminf(m0[iy][1], fminf(fmaf(fi, ya, a0.y), fmaf(fi, yb, b0.y)));
            m0[iy][2] = fminf(m0[iy][2], fminf(fmaf(fi, ya, a0.z), fmaf(fi, yb, b0.z)));
            m0[iy][3] = fminf(m0[iy][3], fminf(fmaf(fi, ya, a0.w), fmaf(fi, yb, b0.w)));
            m1[iy][0] = fminf(m1[iy][0], fminf(fmaf(fi, ya, a1.x), fmaf(fi, yb, b1.x)));
            m1[iy][1] = fminf(m1[iy][1], fminf(fmaf(fi, ya, a1.y), fmaf(fi, yb, b1.y)));
            m1[iy][2] = fminf(m1[iy][2], fminf(fmaf(fi, ya, a1.z), fmaf(fi, yb, b1.z)));
            m1[iy][3] = fminf(m1[iy][3], fminf(fmaf(fi, ya, a1.w), fmaf(fi, yb, b1.w)));
        }
    }

    int cnt = icnt[3 + bc];
    bool has_pos = cnt > 0;
    bool has_neg = cnt < HW;

    float lsum = 0.f;
    size_t pixbase = (size_t)b * HW;
    size_t xbase = ((size_t)b * C_DIM + c) * HW;
    int x0 = (xt << 4) + (tx << 2);
#pragma unroll
    for (int iy = 0; iy < 4; ++iy) {
        int y = ybase + iy;
        float y2 = (float)(y * y);
        size_t rowoff = (size_t)y * W_DIM + x0;
        float4 xv = *(const float4*)(x + xbase + rowoff);
        float4 lv = *(const float4*)(lse + pixbase + rowoff);
        int4 tv = *(const int4*)(tgt + pixbase + rowoff);
#pragma unroll
        for (int j = 0; j < 4; ++j) {
            float d2o = y2 + ((j == 0) ? m0[iy][0] : (j == 1) ? m0[iy][1] : (j == 2) ? m0[iy][2] : m0[iy][3]);
            float d2i = y2 + ((j == 0) ? m1[iy][0] : (j == 1) ? m1[iy][1] : (j == 2) ? m1[iy][2] : m1[iy][3]);
            float dout = sqrtf(d2o), din = sqrtf(d2i);
            float sgn = has_pos ? (has_neg ? (dout - din) : dout) : 0.f;
            float xs = (j == 0) ? xv.x : (j == 1) ? xv.y : (j == 2) ? xv.z : xv.w;
            float ls = (j == 0) ? lv.x : (j == 1) ? lv.y : (j == 2) ? lv.z : lv.w;
            int tt   = (j == 0) ? tv.x : (j == 1) ? tv.y : (j == 2) ? tv.z : tv.w;
            bool vb = (tt >= 0) && (tt < C_DIM);
            float prob = expf(xs - ls);
            lsum += vb ? prob * sgn : 0.f;
        }
    }

    float r = wave_reduce_f(lsum);
    __shared__ float wsum[4];
    if (lane == 0) wsum[wid] = r;
    __syncthreads();
    if (tid == 0) pbound[blk] = (wsum[0] + wsum[1]) + (wsum[2] + wsum[3]);
}

// ---------------- Kernel D: final combine ----------------
__global__ void k_finalize(const float* __restrict__ pce, const float* __restrict__ pinter,
                           const float* __restrict__ ppsum, const float* __restrict__ pbound,
                           const int* __restrict__ icnt, float* __restrict__ out) {
    int tid = threadIdx.x;
    __shared__ double dred[256];
    double s_ce = 0, s_in = 0, s_ps = 0, s_bd = 0;
    for (int k = tid; k < 1024; k += 256) { s_ce += pce[k]; s_in += pinter[k]; s_ps += ppsum[k]; }
    for (int k = tid; k < 512; k += 256) s_bd += pbound[k];

    double sums[4]; double vin[4] = {s_ce, s_in, s_ps, s_bd};
    for (int q = 0; q < 4; ++q) {
        dred[tid] = vin[q];
        __syncthreads();
        for (int s2 = 128; s2; s2 >>= 1) { if (tid < s2) dred[tid] += dred[tid + s2]; __syncthreads(); }
        sums[q] = dred[0];
        __syncthreads();
    }
    if (tid == 0) {
        double ce = sums[0] / (double)NPIX;
        double inter = sums[1];
        double card = sums[2] + (double)icnt[1];
        double dice = 1.0 - (2.0 * inter + 1e-6) / (card + 1e-6);
        double dice_total = 0.1 * ce + 0.9 * dice;
        double bound = sums[3] / ((double)icnt[1] + 1e-8);
        out[0] = (float)(0.1 * ce + 0.8 * dice_total + 0.1 * bound);
    }
}

extern "C" void kernel_launch(void* const* d_in, const int* in_sizes, int n_in,
                              void* d_out, int out_size, void* d_ws, size_t ws_size,
                              hipStream_t stream) {
    const float* x = (const float*)d_in[0];
    const int* tgt = (const int*)d_in[1];
    float* out = (float*)d_out;

    char* ws = (char*)d_ws;
    int* icnt = (int*)ws;
    float* pce    = (float*)(ws + 4096);
    float* pinter = (float*)(ws + 8192);
    float* ppsum  = (float*)(ws + 12288);
    float* pbound = (float*)(ws + 16384);
    float* lse    = (float*)(ws + 32768);
    float* g2     = (float*)(ws + (size_t)(2u << 20));

    hipMemsetAsync(ws, 0, 512, stream);

    k_softmax_stats<<<1024, 256, 0, stream>>>(x, tgt, lse, icnt, pce, pinter, ppsum);
    k_edt_rows<<<1024, 256, 0, stream>>>(tgt, g2);
    k_edt_cols_bound<<<512, 256, 0, stream>>>(g2, x, lse, tgt, icnt, pbound);
    k_finalize<<<1, 256, 0, stream>>>(pce, pinter, ppsum, pbound, icnt, out);
}

// Round 3
// 79.604 us; speedup vs baseline: 2.9173x; 1.1534x over previous
//
#include <hip/hip_runtime.h>
#include <math.h>

// Dims: B=4, C=8, H=W=256
#define B_DIM 4
#define C_DIM 8
#define H_DIM 256
#define W_DIM 256
#define HW 65536
#define NPIX 262144

// ws layout:
// [0, 512)        int icnt[]: [1]=valid_b count, [3+bc]=seed count per (b,c)   (memset 0 each call)
// [4096, 8192)    float pce[1024]
// [8192, 12288)   float pinter[1024]
// [12288,16384)   float ppsum[1024]
// [16384,18432)   float pbound[512]
// [32768, +1MB)   float lse[NPIX]
// [2MB, +8MB)     ushort d1u[64][HW]  job j = bc*2+pol; pol0 seed=cm, pol1 seed=~cm

__device__ __forceinline__ float wave_reduce_f(float v) {
#pragma unroll
    for (int off = 32; off; off >>= 1) v += __shfl_xor(v, off, 64);
    return v;
}

// ---------------- Kernel A: softmax stats (lse map, CE/Dice partials, counts) ----------------
__global__ void k_softmax_stats(const float* __restrict__ x,
                                const int* __restrict__ tgt,
                                float* __restrict__ lse_out,
                                int* __restrict__ icnt,
                                float* __restrict__ pce,
                                float* __restrict__ pinter,
                                float* __restrict__ ppsum) {
    int bi = blockIdx.x;
    int tid = threadIdx.x;
    int p = bi * 256 + tid;
    int lane = tid & 63, wid = tid >> 6;
    int b = p >> 16;
    const float* base = x + (size_t)b * C_DIM * HW + (p & (HW - 1));

    float v[C_DIM];
    float m = -1e30f;
#pragma unroll
    for (int c = 0; c < C_DIM; ++c) { v[c] = base[(size_t)c * HW]; m = fmaxf(m, v[c]); }
    float s = 0.f;
#pragma unroll
    for (int c = 0; c < C_DIM; ++c) s += expf(v[c] - m);
    float lse = m + logf(s);
    lse_out[p] = lse;

    int t = tgt[p];
    bool valid_d = (t >= 0);
    bool valid_b = valid_d && (t < C_DIM);
    int tc = valid_b ? t : 0;
    float vt = v[0];
#pragma unroll
    for (int c = 1; c < C_DIM; ++c) vt = (tc == c) ? v[c] : vt;

    float ce = lse - vt;
    float psum = 0.f;
#pragma unroll
    for (int c = 0; c < C_DIM; ++c) psum += expf(v[c] - lse);
    float inter = valid_b ? expf(vt - lse) : 0.f;
    float psum_m = valid_d ? psum : 0.f;

    __shared__ float ws_ce[4], ws_in[4], ws_ps[4];
    __shared__ int cnt_b[4];
    __shared__ int hist[C_DIM];
    if (tid < C_DIM) hist[tid] = 0;
    __syncthreads();

    float r_ce = wave_reduce_f(ce);
    float r_in = wave_reduce_f(inter);
    float r_ps = wave_reduce_f(psum_m);
    unsigned long long mb = __ballot(valid_b);
#pragma unroll
    for (int c = 0; c < C_DIM; ++c) {
        unsigned long long mc = __ballot(valid_b && (t == c));
        if (lane == 0 && mc) atomicAdd(&hist[c], __popcll(mc));
    }
    if (lane == 0) {
        ws_ce[wid] = r_ce; ws_in[wid] = r_in; ws_ps[wid] = r_ps;
        cnt_b[wid] = __popcll(mb);
    }
    __syncthreads();
    if (tid == 0) {
        pce[bi]    = (ws_ce[0] + ws_ce[1]) + (ws_ce[2] + ws_ce[3]);
        pinter[bi] = (ws_in[0] + ws_in[1]) + (ws_in[2] + ws_in[3]);
        ppsum[bi]  = (ws_ps[0] + ws_ps[1]) + (ws_ps[2] + ws_ps[3]);
        atomicAdd(&icnt[1], (cnt_b[0] + cnt_b[1]) + (cnt_b[2] + cnt_b[3]));
    }
    if (tid < C_DIM && hist[tid] > 0) atomicAdd(&icnt[3 + b * C_DIM + tid], hist[tid]);
}

// ---------------- Kernel B: horizontal EDT via ballot bit-tricks; stores d1 as u16 ----------------
__global__ void k_edt_rows(const int* __restrict__ tgt, unsigned short* __restrict__ d1u) {
    int bi = blockIdx.x;                 // [0,1024): b*256 + y
    int b = bi >> 8, y = bi & 255;
    int i = threadIdx.x;
    int lane = i & 63, wid = i >> 6;

    int t = tgt[(size_t)b * HW + (size_t)y * W_DIM + i];
    bool valid = (t >= 0) && (t < C_DIM);

    __shared__ unsigned long long wmask[C_DIM][4];
#pragma unroll
    for (int c = 0; c < C_DIM; ++c) {
        unsigned long long mc = __ballot(valid && (t == c));
        if (lane == 0) wmask[c][wid] = mc;
    }
    __syncthreads();

    unsigned long long lm_le = (~0ull) >> (63 - lane);
    unsigned long long lm_ge = (~0ull) << lane;

#pragma unroll 1
    for (int c = 0; c < C_DIM; ++c) {
        unsigned long long m0 = wmask[c][wid];
#pragma unroll
        for (int pol = 0; pol < 2; ++pol) {
            unsigned long long mk = pol ? ~m0 : m0;
            unsigned long long mle = mk & lm_le;
            unsigned long long mge = mk & lm_ge;
            int last, next;
            if (mle) last = (wid << 6) + 63 - __builtin_clzll(mle);
            else {
                last = -1000;
                for (int w = wid - 1; w >= 0; --w) {
                    unsigned long long mw = pol ? ~wmask[c][w] : wmask[c][w];
                    if (mw) { last = (w << 6) + 63 - __builtin_clzll(mw); break; }
                }
            }
            if (mge) next = (wid << 6) + __builtin_ctzll(mge);
            else {
                next = 100000;
                for (int w = wid + 1; w < 4; ++w) {
                    unsigned long long mw = pol ? ~wmask[c][w] : wmask[c][w];
                    if (mw) { next = (w << 6) + __builtin_ctzll(mw); break; }
                }
            }
            int d1 = min(min(i - last, next - i), 512);
            int j = ((b * C_DIM + c) << 1) + pol;
            d1u[(size_t)j * HW + (size_t)y * W_DIM + i] = (unsigned short)d1;
        }
    }
}

// ---------------- Kernel C: windowed exact vertical envelope + boundary sum ----------------
// Window bound: dist2[y,x] <= g2[y,x] (candidate yp=y) => only |y-yp| <= sqrt(g2[y,x]) matters.
#define LDS_PITCH 20   // floats; 80B rows: 16B-aligned, bank-start cycles by 20 mod 32
__global__ void __launch_bounds__(256) k_edt_cols_bound(
    const unsigned short* __restrict__ d1u, const float* __restrict__ x,
    const float* __restrict__ lse, const int* __restrict__ tgt,
    const int* __restrict__ icnt, float* __restrict__ pbound) {
    int blk = blockIdx.x;            // [0, 512)
    int bc = blk >> 4;               // [0, 32)
    int xt = blk & 15;               // 16-column tile
    int b = bc >> 3, c = bc & 7;
    int tid = threadIdx.x;
    int ty = tid >> 2;               // 0..63 -> ybase = ty*4
    int tx = tid & 3;                // 0..3  -> x = xt*16 + tx*4 ..+3
    int lane = tid & 63, wid = tid >> 6;

    __shared__ float h[2][H_DIM][LDS_PITCH];

    // stage both polarity planes for this column tile; square d1 on the way in
    {
        size_t j0 = (size_t)(bc << 1) * HW;
#pragma unroll
        for (int ss = 0; ss < 2; ++ss) {
            int s = tid + (ss << 8);          // [0,512): pol = s>>8, yp = s&255
            int pol = s >> 8, yp = s & 255;
            const unsigned short* src = d1u + j0 + (size_t)pol * HW + (size_t)yp * W_DIM + (xt << 4);
            ushort4 u0 = *(const ushort4*)(src);
            ushort4 u1 = *(const ushort4*)(src + 4);
            ushort4 u2 = *(const ushort4*)(src + 8);
            ushort4 u3 = *(const ushort4*)(src + 12);
            float* dst = &h[pol][yp][0];
            float4 f;
            f.x = (float)u0.x * (float)u0.x; f.y = (float)u0.y * (float)u0.y;
            f.z = (float)u0.z * (float)u0.z; f.w = (float)u0.w * (float)u0.w;
            *(float4*)(dst + 0) = f;
            f.x = (float)u1.x * (float)u1.x; f.y = (float)u1.y * (float)u1.y;
            f.z = (float)u1.z * (float)u1.z; f.w = (float)u1.w * (float)u1.w;
            *(float4*)(dst + 4) = f;
            f.x = (float)u2.x * (float)u2.x; f.y = (float)u2.y * (float)u2.y;
            f.z = (float)u2.z * (float)u2.z; f.w = (float)u2.w * (float)u2.w;
            *(float4*)(dst + 8) = f;
            f.x = (float)u3.x * (float)u3.x; f.y = (float)u3.y * (float)u3.y;
            f.z = (float)u3.z * (float)u3.z; f.w = (float)u3.w * (float)u3.w;
            *(float4*)(dst + 12) = f;
        }
    }
    __syncthreads();

    int ybase = ty << 2;
    float m0[4][4], m1[4][4];

#pragma unroll
    for (int pol = 0; pol < 2; ++pol) {
        // window radius = max over the 4x4 tile of sqrt(g2)
        float gmax = 0.f;
#pragma unroll
        for (int iy = 0; iy < 4; ++iy) {
            float4 g = *(float4*)&h[pol][ybase + iy][tx << 2];
            gmax = fmaxf(gmax, fmaxf(fmaxf(g.x, g.y), fmaxf(g.z, g.w)));
        }
        int r = (int)sqrtf(gmax) + 1;     // overestimate-safe
        int ylo = max(0, ybase - r);
        int yhi = min(H_DIM - 1, ybase + 3 + r);

        float (*m)[4] = pol ? m1 : m0;
#pragma unroll
        for (int iy = 0; iy < 4; ++iy)
#pragma unroll
            for (int j = 0; j < 4; ++j) m[iy][j] = 1e30f;

        for (int yp = ylo; yp <= yhi; ++yp) {
            float4 hv = *(float4*)&h[pol][yp][tx << 2];
            float dy0 = (float)(ybase - yp);
#pragma unroll
            for (int iy = 0; iy < 4; ++iy) {
                float dy = dy0 + (float)iy;
                m[iy][0] = fminf(m[iy][0], fmaf(dy, dy, hv.x));
                m[iy][1] = fminf(m[iy][1], fmaf(dy, dy, hv.y));
                m[iy][2] = fminf(m[iy][2], fmaf(dy, dy, hv.z));
                m[iy][3] = fminf(m[iy][3], fmaf(dy, dy, hv.w));
            }
        }
    }

    int cnt = icnt[3 + bc];
    bool has_pos = cnt > 0;
    bool has_neg = cnt < HW;

    float lsum = 0.f;
    size_t pixbase = (size_t)b * HW;
    size_t xbase = ((size_t)b * C_DIM + c) * HW;
    int x0 = (xt << 4) + (tx << 2);
#pragma unroll
    for (int iy = 0; iy < 4; ++iy) {
        int y = ybase + iy;
        size_t rowoff = (size_t)y * W_DIM + x0;
        float4 xv = *(const float4*)(x + xbase + rowoff);
        float4 lv = *(const float4*)(lse + pixbase + rowoff);
        int4 tv = *(const int4*)(tgt + pixbase + rowoff);
#pragma unroll
        for (int j = 0; j < 4; ++j) {
            float dout = sqrtf(m0[iy][j]);
            float din  = sqrtf(m1[iy][j]);
            float sgn = has_pos ? (has_neg ? (dout - din) : dout) : 0.f;
            float xs = (j == 0) ? xv.x : (j == 1) ? xv.y : (j == 2) ? xv.z : xv.w;
            float ls = (j == 0) ? lv.x : (j == 1) ? lv.y : (j == 2) ? lv.z : lv.w;
            int tt   = (j == 0) ? tv.x : (j == 1) ? tv.y : (j == 2) ? tv.z : tv.w;
            bool vb = (tt >= 0) && (tt < C_DIM);
            float prob = expf(xs - ls);
            lsum += vb ? prob * sgn : 0.f;
        }
    }

    float r2 = wave_reduce_f(lsum);
    __shared__ float wsum[4];
    if (lane == 0) wsum[wid] = r2;
    __syncthreads();
    if (tid == 0) pbound[blk] = (wsum[0] + wsum[1]) + (wsum[2] + wsum[3]);
}

// ---------------- Kernel D: final combine ----------------
__global__ void k_finalize(const float* __restrict__ pce, const float* __restrict__ pinter,
                           const float* __restrict__ ppsum, const float* __restrict__ pbound,
                           const int* __restrict__ icnt, float* __restrict__ out) {
    int tid = threadIdx.x;
    __shared__ double dred[256];
    double s_ce = 0, s_in = 0, s_ps = 0, s_bd = 0;
    for (int k = tid; k < 1024; k += 256) { s_ce += pce[k]; s_in += pinter[k]; s_ps += ppsum[k]; }
    for (int k = tid; k < 512; k += 256) s_bd += pbound[k];

    double sums[4]; double vin[4] = {s_ce, s_in, s_ps, s_bd};
    for (int q = 0; q < 4; ++q) {
        dred[tid] = vin[q];
        __syncthreads();
        for (int s2 = 128; s2; s2 >>= 1) { if (tid < s2) dred[tid] += dred[tid + s2]; __syncthreads(); }
        sums[q] = dred[0];
        __syncthreads();
    }
    if (tid == 0) {
        double ce = sums[0] / (double)NPIX;
        double inter = sums[1];
        double card = sums[2] + (double)icnt[1];
        double dice = 1.0 - (2.0 * inter + 1e-6) / (card + 1e-6);
        double dice_total = 0.1 * ce + 0.9 * dice;
        double bound = sums[3] / ((double)icnt[1] + 1e-8);
        out[0] = (float)(0.1 * ce + 0.8 * dice_total + 0.1 * bound);
    }
}

extern "C" void kernel_launch(void* const* d_in, const int* in_sizes, int n_in,
                              void* d_out, int out_size, void* d_ws, size_t ws_size,
                              hipStream_t stream) {
    const float* x = (const float*)d_in[0];
    const int* tgt = (const int*)d_in[1];
    float* out = (float*)d_out;

    char* ws = (char*)d_ws;
    int* icnt = (int*)ws;
    float* pce    = (float*)(ws + 4096);
    float* pinter = (float*)(ws + 8192);
    float* ppsum  = (float*)(ws + 12288);
    float* pbound = (float*)(ws + 16384);
    float* lse    = (float*)(ws + 32768);
    unsigned short* d1u = (unsigned short*)(ws + (size_t)(2u << 20));

    hipMemsetAsync(ws, 0, 512, stream);

    k_softmax_stats<<<1024, 256, 0, stream>>>(x, tgt, lse, icnt, pce, pinter, ppsum);
    k_edt_rows<<<1024, 256, 0, stream>>>(tgt, d1u);
    k_edt_cols_bound<<<512, 256, 0, stream>>>(d1u, x, lse, tgt, icnt, pbound);
    k_finalize<<<1, 256, 0, stream>>>(pce, pinter, ppsum, pbound, icnt, out);
}

// Round 4
// 55.718 us; speedup vs baseline: 4.1679x; 1.4287x over previous
//
#include <hip/hip_runtime.h>
#include <math.h>

// Dims: B=4, C=8, H=W=256
#define B_DIM 4
#define C_DIM 8
#define H_DIM 256
#define W_DIM 256
#define HW 65536
#define NPIX 262144

// ws layout (no zero-init required; every slot written every call):
// [0,     4096)   float pce[1024]
// [4096,  8192)   float pinter[1024]
// [8192, 16384)   int2  pcnt[1024]      {cnt_valid_d, cnt_valid_b} per block
// [16384,18432)   float pbound[512]
// [20480,36864)   uchar rowflagP[64*256]
// [65536,+1MB)    float lse[NPIX]
// [2MB,  +8MB)    ushort d1u[64][HW]    j = (b*8+c)*2+pol; pol0 seed=cm, pol1 seed=~cm

__device__ __forceinline__ float wave_reduce_f(float v) {
#pragma unroll
    for (int off = 32; off; off >>= 1) v += __shfl_xor(v, off, 64);
    return v;
}

// ------------- Kernel 1: fused softmax stats + horizontal EDT for one (b,y) row -------------
__global__ void __launch_bounds__(256) k_row(
    const float* __restrict__ x, const int* __restrict__ tgt,
    float* __restrict__ lse_out, float* __restrict__ pce, float* __restrict__ pinter,
    int2* __restrict__ pcnt, unsigned char* __restrict__ rowflagP,
    unsigned short* __restrict__ d1u) {
    int bi = blockIdx.x;                 // [0,1024): b*256 + y
    int b = bi >> 8, y = bi & 255;
    int i = threadIdx.x;                 // column
    int lane = i & 63, wid = i >> 6;
    size_t rowbase = (size_t)b * HW + (size_t)y * W_DIM;

    // ---- softmax / CE / Dice stats ----
    const float* xb = x + (size_t)b * C_DIM * HW + (size_t)y * W_DIM + i;
    float v[C_DIM];
    float m = -1e30f;
#pragma unroll
    for (int c = 0; c < C_DIM; ++c) { v[c] = xb[(size_t)c * HW]; m = fmaxf(m, v[c]); }
    float s = 0.f;
#pragma unroll
    for (int c = 0; c < C_DIM; ++c) s += expf(v[c] - m);
    float lse = m + logf(s);
    lse_out[rowbase + i] = lse;

    int t = tgt[rowbase + i];
    bool valid_d = (t >= 0);
    bool valid_b = valid_d && (t < C_DIM);
    int tc = valid_b ? t : 0;
    float vt = v[0];
#pragma unroll
    for (int c = 1; c < C_DIM; ++c) vt = (tc == c) ? v[c] : vt;

    float ce = lse - vt;
    float inter = valid_b ? expf(vt - lse) : 0.f;

    __shared__ float ws_ce[4], ws_in[4];
    __shared__ int ws_cd[4], ws_cb[4];
    float r_ce = wave_reduce_f(ce);
    float r_in = wave_reduce_f(inter);
    unsigned long long md = __ballot(valid_d);
    unsigned long long mbv = __ballot(valid_b);
    if (lane == 0) {
        ws_ce[wid] = r_ce; ws_in[wid] = r_in;
        ws_cd[wid] = __popcll(md); ws_cb[wid] = __popcll(mbv);
    }

    // ---- row EDT via ballot masks ----
    __shared__ unsigned long long wmask[C_DIM][4];
#pragma unroll
    for (int c = 0; c < C_DIM; ++c) {
        unsigned long long mc = __ballot(valid_b && (t == c));
        if (lane == 0) wmask[c][wid] = mc;
    }
    __syncthreads();

    if (i == 0) {
        pce[bi] = (ws_ce[0] + ws_ce[1]) + (ws_ce[2] + ws_ce[3]);
        pinter[bi] = (ws_in[0] + ws_in[1]) + (ws_in[2] + ws_in[3]);
        pcnt[bi] = make_int2((ws_cd[0] + ws_cd[1]) + (ws_cd[2] + ws_cd[3]),
                             (ws_cb[0] + ws_cb[1]) + (ws_cb[2] + ws_cb[3]));
    }
    if (i < 16) {   // per-(c,pol) row seed flags
        int c = i >> 1, pol = i & 1;
        unsigned long long o = wmask[c][0] | wmask[c][1] | wmask[c][2] | wmask[c][3];
        unsigned long long a = wmask[c][0] & wmask[c][1] & wmask[c][2] & wmask[c][3];
        bool any = pol ? (a != ~0ull) : (o != 0ull);
        int j = ((b * C_DIM + c) << 1) + pol;
        rowflagP[(j << 8) + y] = any ? 1 : 0;
    }

    unsigned long long lm_le = (~0ull) >> (63 - lane);
    unsigned long long lm_ge = (~0ull) << lane;

#pragma unroll 1
    for (int c = 0; c < C_DIM; ++c) {
        unsigned long long m0 = wmask[c][wid];
#pragma unroll
        for (int pol = 0; pol < 2; ++pol) {
            unsigned long long mk = pol ? ~m0 : m0;
            unsigned long long mle = mk & lm_le;
            unsigned long long mge = mk & lm_ge;
            int last, next;
            if (mle) last = (wid << 6) + 63 - __builtin_clzll(mle);
            else {
                last = -1000;
                for (int w = wid - 1; w >= 0; --w) {
                    unsigned long long mw = pol ? ~wmask[c][w] : wmask[c][w];
                    if (mw) { last = (w << 6) + 63 - __builtin_clzll(mw); break; }
                }
            }
            if (mge) next = (wid << 6) + __builtin_ctzll(mge);
            else {
                next = 100000;
                for (int w = wid + 1; w < 4; ++w) {
                    unsigned long long mw = pol ? ~wmask[c][w] : wmask[c][w];
                    if (mw) { next = (w << 6) + __builtin_ctzll(mw); break; }
                }
            }
            int d1 = min(min(i - last, next - i), 512);
            int j = ((b * C_DIM + c) << 1) + pol;
            d1u[(size_t)j * HW + (size_t)y * W_DIM + i] = (unsigned short)d1;
        }
    }
}

// ------------- Kernel 2: windowed exact vertical envelope + boundary sum -------------
#define LDS_PITCH 20
__global__ void __launch_bounds__(256) k_edt_cols_bound(
    const unsigned short* __restrict__ d1u, const float* __restrict__ x,
    const float* __restrict__ lse, const int* __restrict__ tgt,
    const unsigned char* __restrict__ rowflagP, float* __restrict__ pbound) {
    int blk = blockIdx.x;            // [0, 512)
    int bc = blk >> 4;               // [0, 32)
    int xt = blk & 15;
    int b = bc >> 3, c = bc & 7;
    int tid = threadIdx.x;
    int ty = tid >> 2;
    int tx = tid & 3;
    int lane = tid & 63, wid = tid >> 6;

    __shared__ float h[2][H_DIM][LDS_PITCH];
    __shared__ int anyf[2];

    if (tid < 2) anyf[tid] = 0;
    __syncthreads();
    {
        int j0 = bc << 1;
        unsigned char f0 = rowflagP[(j0 << 8) + tid];
        unsigned char f1 = rowflagP[((j0 + 1) << 8) + tid];
        unsigned long long b0 = __ballot(f0 != 0);
        unsigned long long b1 = __ballot(f1 != 0);
        if (lane == 0) {
            if (b0) atomicOr(&anyf[0], 1);
            if (b1) atomicOr(&anyf[1], 1);
        }
    }

    {
        size_t j0 = (size_t)(bc << 1) * HW;
#pragma unroll
        for (int ss = 0; ss < 2; ++ss) {
            int s = tid + (ss << 8);
            int pol = s >> 8, yp = s & 255;
            const unsigned short* src = d1u + j0 + (size_t)pol * HW + (size_t)yp * W_DIM + (xt << 4);
            ushort4 u0 = *(const ushort4*)(src);
            ushort4 u1 = *(const ushort4*)(src + 4);
            ushort4 u2 = *(const ushort4*)(src + 8);
            ushort4 u3 = *(const ushort4*)(src + 12);
            float* dst = &h[pol][yp][0];
            float4 f;
            f.x = (float)u0.x * (float)u0.x; f.y = (float)u0.y * (float)u0.y;
            f.z = (float)u0.z * (float)u0.z; f.w = (float)u0.w * (float)u0.w;
            *(float4*)(dst + 0) = f;
            f.x = (float)u1.x * (float)u1.x; f.y = (float)u1.y * (float)u1.y;
            f.z = (float)u1.z * (float)u1.z; f.w = (float)u1.w * (float)u1.w;
            *(float4*)(dst + 4) = f;
            f.x = (float)u2.x * (float)u2.x; f.y = (float)u2.y * (float)u2.y;
            f.z = (float)u2.z * (float)u2.z; f.w = (float)u2.w * (float)u2.w;
            *(float4*)(dst + 8) = f;
            f.x = (float)u3.x * (float)u3.x; f.y = (float)u3.y * (float)u3.y;
            f.z = (float)u3.z * (float)u3.z; f.w = (float)u3.w * (float)u3.w;
            *(float4*)(dst + 12) = f;
        }
    }
    __syncthreads();

    int ybase = ty << 2;
    float m0[4][4], m1[4][4];

#pragma unroll
    for (int pol = 0; pol < 2; ++pol) {
        float gmax = 0.f;
#pragma unroll
        for (int iy = 0; iy < 4; ++iy) {
            float4 g = *(float4*)&h[pol][ybase + iy][tx << 2];
            gmax = fmaxf(gmax, fmaxf(fmaxf(g.x, g.y), fmaxf(g.z, g.w)));
        }
        int r = (int)sqrtf(gmax) + 1;
        int ylo = max(0, ybase - r);
        int yhi = min(H_DIM - 1, ybase + 3 + r);

        float (*mm)[4] = pol ? m1 : m0;
#pragma unroll
        for (int iy = 0; iy < 4; ++iy)
#pragma unroll
            for (int j = 0; j < 4; ++j) mm[iy][j] = 1e30f;

        for (int yp = ylo; yp <= yhi; ++yp) {
            float4 hv = *(float4*)&h[pol][yp][tx << 2];
            float dy0 = (float)(ybase - yp);
#pragma unroll
            for (int iy = 0; iy < 4; ++iy) {
                float dy = dy0 + (float)iy;
                mm[iy][0] = fminf(mm[iy][0], fmaf(dy, dy, hv.x));
                mm[iy][1] = fminf(mm[iy][1], fmaf(dy, dy, hv.y));
                mm[iy][2] = fminf(mm[iy][2], fmaf(dy, dy, hv.z));
                mm[iy][3] = fminf(mm[iy][3], fmaf(dy, dy, hv.w));
            }
        }
    }

    bool has_pos = anyf[0] != 0;
    bool has_neg = anyf[1] != 0;

    float lsum = 0.f;
    size_t pixbase = (size_t)b * HW;
    size_t xbase = ((size_t)b * C_DIM + c) * HW;
    int x0 = (xt << 4) + (tx << 2);
#pragma unroll
    for (int iy = 0; iy < 4; ++iy) {
        int y = ybase + iy;
        size_t rowoff = (size_t)y * W_DIM + x0;
        float4 xv = *(const float4*)(x + xbase + rowoff);
        float4 lv = *(const float4*)(lse + pixbase + rowoff);
        int4 tv = *(const int4*)(tgt + pixbase + rowoff);
#pragma unroll
        for (int j = 0; j < 4; ++j) {
            float dout = sqrtf(m0[iy][j]);
            float din  = sqrtf(m1[iy][j]);
            float sgn = has_pos ? (has_neg ? (dout - din) : dout) : 0.f;
            float xs = (j == 0) ? xv.x : (j == 1) ? xv.y : (j == 2) ? xv.z : xv.w;
            float ls = (j == 0) ? lv.x : (j == 1) ? lv.y : (j == 2) ? lv.z : lv.w;
            int tt   = (j == 0) ? tv.x : (j == 1) ? tv.y : (j == 2) ? tv.z : tv.w;
            bool vb = (tt >= 0) && (tt < C_DIM);
            float prob = expf(xs - ls);
            lsum += vb ? prob * sgn : 0.f;
        }
    }

    float r2 = wave_reduce_f(lsum);
    __shared__ float wsum[4];
    if (lane == 0) wsum[wid] = r2;
    __syncthreads();
    if (tid == 0) pbound[blk] = (wsum[0] + wsum[1]) + (wsum[2] + wsum[3]);
}

// ------------- Kernel 3: final combine -------------
__global__ void k_finalize(const float* __restrict__ pce, const float* __restrict__ pinter,
                           const int2* __restrict__ pcnt, const float* __restrict__ pbound,
                           float* __restrict__ out) {
    int tid = threadIdx.x;
    __shared__ double dred[256];
    double s_ce = 0, s_in = 0, s_bd = 0;
    double c_d = 0, c_b = 0;
    for (int k = tid; k < 1024; k += 256) {
        s_ce += pce[k]; s_in += pinter[k];
        int2 cc = pcnt[k]; c_d += (double)cc.x; c_b += (double)cc.y;
    }
    for (int k = tid; k < 512; k += 256) s_bd += pbound[k];

    double sums[4]; double vin[4] = {s_ce, s_in, s_bd, c_d * 4194304.0 + c_b};
    for (int q = 0; q < 4; ++q) {
        dred[tid] = vin[q];
        __syncthreads();
        for (int s2 = 128; s2; s2 >>= 1) { if (tid < s2) dred[tid] += dred[tid + s2]; __syncthreads(); }
        sums[q] = dred[0];
        __syncthreads();
    }
    if (tid == 0) {
        double packed = sums[3];
        double cd = floor(packed / 4194304.0 + 1e-9);   // exact: both ints < 2^19
        double cb = packed - cd * 4194304.0;
        double ce = sums[0] / (double)NPIX;
        double inter = sums[1];
        double card = cd + cb;
        double dice = 1.0 - (2.0 * inter + 1e-6) / (card + 1e-6);
        double dice_total = 0.1 * ce + 0.9 * dice;
        double bound = sums[2] / (cb + 1e-8);
        out[0] = (float)(0.1 * ce + 0.8 * dice_total + 0.1 * bound);
    }
}

extern "C" void kernel_launch(void* const* d_in, const int* in_sizes, int n_in,
                              void* d_out, int out_size, void* d_ws, size_t ws_size,
                              hipStream_t stream) {
    const float* x = (const float*)d_in[0];
    const int* tgt = (const int*)d_in[1];
    float* out = (float*)d_out;

    char* ws = (char*)d_ws;
    float* pce    = (float*)(ws + 0);
    float* pinter = (float*)(ws + 4096);
    int2*  pcnt   = (int2*)(ws + 8192);
    float* pbound = (float*)(ws + 16384);
    unsigned char* rowflagP = (unsigned char*)(ws + 20480);
    float* lse    = (float*)(ws + 65536);
    unsigned short* d1u = (unsigned short*)(ws + (size_t)(2u << 20));

    k_row<<<1024, 256, 0, stream>>>(x, tgt, lse, pce, pinter, pcnt, rowflagP, d1u);
    k_edt_cols_bound<<<512, 256, 0, stream>>>(d1u, x, lse, tgt, rowflagP, pbound);
    k_finalize<<<1, 256, 0, stream>>>(pce, pinter, pcnt, pbound, out);
}

// Round 5
// 52.531 us; speedup vs baseline: 4.4208x; 1.0607x over previous
//
#include <hip/hip_runtime.h>
#include <math.h>

// Dims: B=4, C=8, H=W=256
#define B_DIM 4
#define C_DIM 8
#define H_DIM 256
#define W_DIM 256
#define HW 65536
#define NPIX 262144

// ws layout (no zero-init required; every slot written every call):
// [0,     4096)   float pce[1024]
// [4096,  8192)   float pinter[1024]
// [8192, 16384)   int2  pcnt[1024]      {cnt_valid_d, cnt_valid_b} per row-block
// [16384,18432)   float pbound[512]
// [18432,18436)   uint  done            (zeroed by k_row block 0 each call)
// [20480,36864)   uchar rowflagP[64*256]
// [65536,+1MB)    float lse[NPIX]
// [2MB,  +8MB)    uint  d1p[32][HW]     plane bc; word = d1_pol0 | (d1_pol1<<16)

__device__ __forceinline__ float wave_reduce_f(float v) {
#pragma unroll
    for (int off = 32; off; off >>= 1) v += __shfl_xor(v, off, 64);
    return v;
}

// ------------- Kernel 1: fused softmax stats + horizontal EDT for one (b,y) row -------------
__global__ void __launch_bounds__(256) k_row(
    const float* __restrict__ x, const int* __restrict__ tgt,
    float* __restrict__ lse_out, float* __restrict__ pce, float* __restrict__ pinter,
    int2* __restrict__ pcnt, unsigned char* __restrict__ rowflagP,
    unsigned int* __restrict__ d1p, unsigned int* __restrict__ done) {
    int bi = blockIdx.x;                 // [0,1024): b*256 + y
    int b = bi >> 8, y = bi & 255;
    int i = threadIdx.x;                 // column
    int lane = i & 63, wid = i >> 6;
    size_t rowbase = (size_t)b * HW + (size_t)y * W_DIM;

    if (bi == 0 && i == 0) *done = 0u;   // completes before kernel 2 starts (same stream)

    // ---- softmax / CE / Dice stats ----
    const float* xb = x + (size_t)b * C_DIM * HW + (size_t)y * W_DIM + i;
    float v[C_DIM];
    float m = -1e30f;
#pragma unroll
    for (int c = 0; c < C_DIM; ++c) { v[c] = xb[(size_t)c * HW]; m = fmaxf(m, v[c]); }
    float s = 0.f;
#pragma unroll
    for (int c = 0; c < C_DIM; ++c) s += __expf(v[c] - m);
    float lse = m + __logf(s);
    lse_out[rowbase + i] = lse;

    int t = tgt[rowbase + i];
    bool valid_d = (t >= 0);
    bool valid_b = valid_d && (t < C_DIM);
    int tc = valid_b ? t : 0;
    float vt = v[0];
#pragma unroll
    for (int c = 1; c < C_DIM; ++c) vt = (tc == c) ? v[c] : vt;

    float ce = lse - vt;
    float inter = valid_b ? __expf(vt - m) * (1.0f / s) : 0.f;

    __shared__ float ws_ce[4], ws_in[4];
    __shared__ int ws_cd[4], ws_cb[4];
    float r_ce = wave_reduce_f(ce);
    float r_in = wave_reduce_f(inter);
    unsigned long long md = __ballot(valid_d);
    unsigned long long mbv = __ballot(valid_b);
    if (lane == 0) {
        ws_ce[wid] = r_ce; ws_in[wid] = r_in;
        ws_cd[wid] = __popcll(md); ws_cb[wid] = __popcll(mbv);
    }

    // ---- row EDT via ballot masks ----
    __shared__ unsigned long long wmask[C_DIM][4];
#pragma unroll
    for (int c = 0; c < C_DIM; ++c) {
        unsigned long long mc = __ballot(valid_b && (t == c));
        if (lane == 0) wmask[c][wid] = mc;
    }
    __syncthreads();

    if (i == 0) {
        pce[bi] = (ws_ce[0] + ws_ce[1]) + (ws_ce[2] + ws_ce[3]);
        pinter[bi] = (ws_in[0] + ws_in[1]) + (ws_in[2] + ws_in[3]);
        pcnt[bi] = make_int2((ws_cd[0] + ws_cd[1]) + (ws_cd[2] + ws_cd[3]),
                             (ws_cb[0] + ws_cb[1]) + (ws_cb[2] + ws_cb[3]));
    }
    if (i < 16) {   // per-(c,pol) row seed flags
        int c = i >> 1, pol = i & 1;
        unsigned long long o = wmask[c][0] | wmask[c][1] | wmask[c][2] | wmask[c][3];
        unsigned long long a = wmask[c][0] & wmask[c][1] & wmask[c][2] & wmask[c][3];
        bool any = pol ? (a != ~0ull) : (o != 0ull);
        int j = ((b * C_DIM + c) << 1) + pol;
        rowflagP[(j << 8) + y] = any ? 1 : 0;
    }

    unsigned long long lm_le = (~0ull) >> (63 - lane);
    unsigned long long lm_ge = (~0ull) << lane;

#pragma unroll 1
    for (int c = 0; c < C_DIM; ++c) {
        unsigned long long m0 = wmask[c][wid];
        int d1v[2];
#pragma unroll
        for (int pol = 0; pol < 2; ++pol) {
            unsigned long long mk = pol ? ~m0 : m0;
            unsigned long long mle = mk & lm_le;
            unsigned long long mge = mk & lm_ge;
            int last, next;
            if (mle) last = (wid << 6) + 63 - __builtin_clzll(mle);
            else {
                last = -1000;
                for (int w = wid - 1; w >= 0; --w) {
                    unsigned long long mw = pol ? ~wmask[c][w] : wmask[c][w];
                    if (mw) { last = (w << 6) + 63 - __builtin_clzll(mw); break; }
                }
            }
            if (mge) next = (wid << 6) + __builtin_ctzll(mge);
            else {
                next = 100000;
                for (int w = wid + 1; w < 4; ++w) {
                    unsigned long long mw = pol ? ~wmask[c][w] : wmask[c][w];
                    if (mw) { next = (w << 6) + __builtin_ctzll(mw); break; }
                }
            }
            d1v[pol] = min(min(i - last, next - i), 512);
        }
        int bc = b * C_DIM + c;
        d1p[(size_t)bc * HW + (size_t)y * W_DIM + i] =
            (unsigned int)d1v[0] | ((unsigned int)d1v[1] << 16);
    }
}

// ------------- Kernel 2: windowed exact vertical envelope + boundary sum + finalize -------------
__global__ void __launch_bounds__(256) k_cols_fin(
    const unsigned int* __restrict__ d1p, const float* __restrict__ x,
    const float* __restrict__ lse, const int* __restrict__ tgt,
    const unsigned char* __restrict__ rowflagP,
    const float* __restrict__ pce, const float* __restrict__ pinter,
    const int2* __restrict__ pcnt, float* __restrict__ pbound,
    unsigned int* __restrict__ done, float* __restrict__ out) {
    int blk = blockIdx.x;            // [0, 512)
    int bc = blk >> 4;               // [0, 32)
    int xt = blk & 15;
    int b = bc >> 3, c = bc & 7;
    int tid = threadIdx.x;
    int ty = tid >> 2;
    int tx = tid & 3;
    int lane = tid & 63, wid = tid >> 6;

    __shared__ float h[2][H_DIM][16];
    __shared__ int anyf[2];
    __shared__ double dred[256];
    __shared__ float wsum[4];
    __shared__ int sh_last;

    if (tid < 2) anyf[tid] = 0;
    __syncthreads();
    {
        int j0 = bc << 1;
        unsigned char f0 = rowflagP[(j0 << 8) + tid];
        unsigned char f1 = rowflagP[((j0 + 1) << 8) + tid];
        unsigned long long b0 = __ballot(f0 != 0);
        unsigned long long b1 = __ballot(f1 != 0);
        if (lane == 0) {
            if (b0) atomicOr(&anyf[0], 1);
            if (b1) atomicOr(&anyf[1], 1);
        }
    }

    // stage: one packed row (16 u32 = 64B) per thread; unpack, square into h[pol]
    {
        const unsigned int* src = d1p + (size_t)bc * HW + (size_t)tid * W_DIM + (xt << 4);
        uint4 a = *(const uint4*)(src);
        uint4 bq = *(const uint4*)(src + 4);
        uint4 cq = *(const uint4*)(src + 8);
        uint4 dq = *(const uint4*)(src + 12);
        unsigned int w[16] = {a.x, a.y, a.z, a.w, bq.x, bq.y, bq.z, bq.w,
                              cq.x, cq.y, cq.z, cq.w, dq.x, dq.y, dq.z, dq.w};
#pragma unroll
        for (int k = 0; k < 16; ++k) {
            float d0 = (float)(w[k] & 0xFFFFu);
            float d1 = (float)(w[k] >> 16);
            h[0][tid][k] = d0 * d0;
            h[1][tid][k] = d1 * d1;
        }
    }
    __syncthreads();

    int ybase = ty << 2;
    float m0[4][4], m1[4][4];

#pragma unroll
    for (int pol = 0; pol < 2; ++pol) {
        float gmax = 0.f;
#pragma unroll
        for (int iy = 0; iy < 4; ++iy) {
            float4 g = *(float4*)&h[pol][ybase + iy][tx << 2];
            gmax = fmaxf(gmax, fmaxf(fmaxf(g.x, g.y), fmaxf(g.z, g.w)));
        }
        int r = (int)sqrtf(gmax) + 1;
        int ylo = max(0, ybase - r);
        int yhi = min(H_DIM - 1, ybase + 3 + r);

        float (*mm)[4] = pol ? m1 : m0;
#pragma unroll
        for (int iy = 0; iy < 4; ++iy)
#pragma unroll
            for (int j = 0; j < 4; ++j) mm[iy][j] = 1e30f;

        for (int yp = ylo; yp <= yhi; ++yp) {
            float4 hv = *(float4*)&h[pol][yp][tx << 2];
            float dy0 = (float)(ybase - yp);
#pragma unroll
            for (int iy = 0; iy < 4; ++iy) {
                float dy = dy0 + (float)iy;
                mm[iy][0] = fminf(mm[iy][0], fmaf(dy, dy, hv.x));
                mm[iy][1] = fminf(mm[iy][1], fmaf(dy, dy, hv.y));
                mm[iy][2] = fminf(mm[iy][2], fmaf(dy, dy, hv.z));
                mm[iy][3] = fminf(mm[iy][3], fmaf(dy, dy, hv.w));
            }
        }
    }

    bool has_pos = anyf[0] != 0;
    bool has_neg = anyf[1] != 0;

    float lsum = 0.f;
    size_t pixbase = (size_t)b * HW;
    size_t xbase = ((size_t)b * C_DIM + c) * HW;
    int x0 = (xt << 4) + (tx << 2);
#pragma unroll
    for (int iy = 0; iy < 4; ++iy) {
        int y = ybase + iy;
        size_t rowoff = (size_t)y * W_DIM + x0;
        float4 xv = *(const float4*)(x + xbase + rowoff);
        float4 lv = *(const float4*)(lse + pixbase + rowoff);
        int4 tv = *(const int4*)(tgt + pixbase + rowoff);
#pragma unroll
        for (int j = 0; j < 4; ++j) {
            float dout = sqrtf(m0[iy][j]);
            float din  = sqrtf(m1[iy][j]);
            float sgn = has_pos ? (has_neg ? (dout - din) : dout) : 0.f;
            float xs = (j == 0) ? xv.x : (j == 1) ? xv.y : (j == 2) ? xv.z : xv.w;
            float ls = (j == 0) ? lv.x : (j == 1) ? lv.y : (j == 2) ? lv.z : lv.w;
            int tt   = (j == 0) ? tv.x : (j == 1) ? tv.y : (j == 2) ? tv.z : tv.w;
            bool vb = (tt >= 0) && (tt < C_DIM);
            float prob = __expf(xs - ls);
            lsum += vb ? prob * sgn : 0.f;
        }
    }

    float r2 = wave_reduce_f(lsum);
    if (lane == 0) wsum[wid] = r2;
    __syncthreads();
    if (tid == 0) {
        pbound[blk] = (wsum[0] + wsum[1]) + (wsum[2] + wsum[3]);
        __threadfence();
        unsigned int o = atomicAdd(done, 1u);
        sh_last = (o == 511u) ? 1 : 0;
    }
    __syncthreads();
    if (!sh_last) return;

    // ---- last block: final combine ----
    __threadfence();   // acquire: make other blocks' pbound stores visible
    double s_ce = 0, s_in = 0, s_bd = 0, c_d = 0, c_b = 0;
    for (int k = tid; k < 1024; k += 256) {
        s_ce += (double)pce[k]; s_in += (double)pinter[k];
        int2 cc = pcnt[k]; c_d += (double)cc.x; c_b += (double)cc.y;
    }
    for (int k = tid; k < 512; k += 256) s_bd += (double)pbound[k];

    double sums[4]; double vin[4] = {s_ce, s_in, s_bd, c_d * 4194304.0 + c_b};
    for (int q = 0; q < 4; ++q) {
        dred[tid] = vin[q];
        __syncthreads();
        for (int s2 = 128; s2; s2 >>= 1) { if (tid < s2) dred[tid] += dred[tid + s2]; __syncthreads(); }
        sums[q] = dred[0];
        __syncthreads();
    }
    if (tid == 0) {
        double packed = sums[3];
        double cd = floor(packed / 4194304.0 + 1e-9);
        double cb = packed - cd * 4194304.0;
        double ce = sums[0] / (double)NPIX;
        double inter = sums[1];
        double card = cd + cb;
        double dice = 1.0 - (2.0 * inter + 1e-6) / (card + 1e-6);
        double dice_total = 0.1 * ce + 0.9 * dice;
        double bound = sums[2] / (cb + 1e-8);
        out[0] = (float)(0.1 * ce + 0.8 * dice_total + 0.1 * bound);
    }
}

extern "C" void kernel_launch(void* const* d_in, const int* in_sizes, int n_in,
                              void* d_out, int out_size, void* d_ws, size_t ws_size,
                              hipStream_t stream) {
    const float* x = (const float*)d_in[0];
    const int* tgt = (const int*)d_in[1];
    float* out = (float*)d_out;

    char* ws = (char*)d_ws;
    float* pce    = (float*)(ws + 0);
    float* pinter = (float*)(ws + 4096);
    int2*  pcnt   = (int2*)(ws + 8192);
    float* pbound = (float*)(ws + 16384);
    unsigned int* done = (unsigned int*)(ws + 18432);
    unsigned char* rowflagP = (unsigned char*)(ws + 20480);
    float* lse    = (float*)(ws + 65536);
    unsigned int* d1p = (unsigned int*)(ws + (size_t)(2u << 20));

    k_row<<<1024, 256, 0, stream>>>(x, tgt, lse, pce, pinter, pcnt, rowflagP, d1p, done);
    k_cols_fin<<<512, 256, 0, stream>>>(d1p, x, lse, tgt, rowflagP,
                                        pce, pinter, pcnt, pbound, done, out);
}

// Round 6
// 51.248 us; speedup vs baseline: 4.5315x; 1.0250x over previous
//
#include <hip/hip_runtime.h>
#include <math.h>

// Dims: B=4, C=8, H=W=256
#define B_DIM 4
#define C_DIM 8
#define H_DIM 256
#define W_DIM 256
#define HW 65536
#define NPIX 262144

// ws layout (no zero-init required; every slot written every call):
// [0,     4096)   float pce[1024]
// [4096,  8192)   float pinter[1024]
// [8192, 16384)   int2  pcnt[1024]      {cnt_valid_d, cnt_valid_b} per row-block
// [16384,18432)   float pbound[512]
// [18432,18436)   uint  done            (zeroed by k_row block 0 each call)
// [20480,36864)   uchar rowflagP[64*256]
// [65536,+1MB)    float lse[NPIX]
// [2MB,  +8MB)    uint  d1t[32][16][256][16]  tiled: [bc][xt][y][word]; word = d1_pol0 | d1_pol1<<16

__device__ __forceinline__ float wave_reduce_f(float v) {
#pragma unroll
    for (int off = 32; off; off >>= 1) v += __shfl_xor(v, off, 64);
    return v;
}

// ------------- Kernel 1: fused softmax stats + horizontal EDT for one (b,y) row -------------
__global__ void __launch_bounds__(256) k_row(
    const float* __restrict__ x, const int* __restrict__ tgt,
    float* __restrict__ lse_out, float* __restrict__ pce, float* __restrict__ pinter,
    int2* __restrict__ pcnt, unsigned char* __restrict__ rowflagP,
    unsigned int* __restrict__ d1t, unsigned int* __restrict__ done) {
    int bi = blockIdx.x;                 // [0,1024): b*256 + y
    int b = bi >> 8, y = bi & 255;
    int i = threadIdx.x;                 // column
    int lane = i & 63, wid = i >> 6;
    size_t rowbase = (size_t)b * HW + (size_t)y * W_DIM;

    if (bi == 0 && i == 0) *done = 0u;   // stream-ordered before kernel 2

    // ---- softmax / CE / Dice stats ----
    const float* xb = x + (size_t)b * C_DIM * HW + (size_t)y * W_DIM + i;
    float v[C_DIM];
    float m = -1e30f;
#pragma unroll
    for (int c = 0; c < C_DIM; ++c) { v[c] = xb[(size_t)c * HW]; m = fmaxf(m, v[c]); }
    float s = 0.f;
#pragma unroll
    for (int c = 0; c < C_DIM; ++c) s += __expf(v[c] - m);
    float lse = m + __logf(s);
    lse_out[rowbase + i] = lse;

    int t = tgt[rowbase + i];
    bool valid_d = (t >= 0);
    bool valid_b = valid_d && (t < C_DIM);
    int tc = valid_b ? t : 0;
    float vt = v[0];
#pragma unroll
    for (int c = 1; c < C_DIM; ++c) vt = (tc == c) ? v[c] : vt;

    float ce = lse - vt;
    float inter = valid_b ? __expf(vt - m) * (1.0f / s) : 0.f;

    __shared__ float ws_ce[4], ws_in[4];
    __shared__ int ws_cd[4], ws_cb[4];
    float r_ce = wave_reduce_f(ce);
    float r_in = wave_reduce_f(inter);
    unsigned long long md = __ballot(valid_d);
    unsigned long long mbv = __ballot(valid_b);
    if (lane == 0) {
        ws_ce[wid] = r_ce; ws_in[wid] = r_in;
        ws_cd[wid] = __popcll(md); ws_cb[wid] = __popcll(mbv);
    }

    // ---- row EDT via ballot masks ----
    __shared__ unsigned long long wmask[C_DIM][4];
#pragma unroll
    for (int c = 0; c < C_DIM; ++c) {
        unsigned long long mc = __ballot(valid_b && (t == c));
        if (lane == 0) wmask[c][wid] = mc;
    }
    __syncthreads();

    if (i == 0) {
        pce[bi] = (ws_ce[0] + ws_ce[1]) + (ws_ce[2] + ws_ce[3]);
        pinter[bi] = (ws_in[0] + ws_in[1]) + (ws_in[2] + ws_in[3]);
        pcnt[bi] = make_int2((ws_cd[0] + ws_cd[1]) + (ws_cd[2] + ws_cd[3]),
                             (ws_cb[0] + ws_cb[1]) + (ws_cb[2] + ws_cb[3]));
    }
    if (i < 16) {   // per-(c,pol) row seed flags
        int c = i >> 1, pol = i & 1;
        unsigned long long o = wmask[c][0] | wmask[c][1] | wmask[c][2] | wmask[c][3];
        unsigned long long a = wmask[c][0] & wmask[c][1] & wmask[c][2] & wmask[c][3];
        bool any = pol ? (a != ~0ull) : (o != 0ull);
        int j = ((b * C_DIM + c) << 1) + pol;
        rowflagP[(j << 8) + y] = any ? 1 : 0;
    }

    unsigned long long lm_le = (~0ull) >> (63 - lane);
    unsigned long long lm_ge = (~0ull) << lane;

#pragma unroll 1
    for (int c = 0; c < C_DIM; ++c) {
        unsigned long long m0 = wmask[c][wid];
        int d1v[2];
#pragma unroll
        for (int pol = 0; pol < 2; ++pol) {
            unsigned long long mk = pol ? ~m0 : m0;
            unsigned long long mle = mk & lm_le;
            unsigned long long mge = mk & lm_ge;
            int last, next;
            if (mle) last = (wid << 6) + 63 - __builtin_clzll(mle);
            else {
                last = -1000;
                for (int w = wid - 1; w >= 0; --w) {
                    unsigned long long mw = pol ? ~wmask[c][w] : wmask[c][w];
                    if (mw) { last = (w << 6) + 63 - __builtin_clzll(mw); break; }
                }
            }
            if (mge) next = (wid << 6) + __builtin_ctzll(mge);
            else {
                next = 100000;
                for (int w = wid + 1; w < 4; ++w) {
                    unsigned long long mw = pol ? ~wmask[c][w] : wmask[c][w];
                    if (mw) { next = (w << 6) + __builtin_ctzll(mw); break; }
                }
            }
            d1v[pol] = min(min(i - last, next - i), 512);
        }
        int bc = b * C_DIM + c;
        // tiled store: [bc][xt=i>>4][y][word=i&15]
        d1t[(((size_t)bc * 16 + (i >> 4)) * 256 + y) * 16 + (i & 15)] =
            (unsigned int)d1v[0] | ((unsigned int)d1v[1] << 16);
    }
}

// ------------- Kernel 2: windowed exact vertical envelope + boundary sum + finalize -------------
#define LDS_PITCH 20
__global__ void __launch_bounds__(256) k_cols_fin(
    const unsigned int* __restrict__ d1t, const float* __restrict__ x,
    const float* __restrict__ lse, const int* __restrict__ tgt,
    const unsigned char* __restrict__ rowflagP,
    const float* __restrict__ pce, const float* __restrict__ pinter,
    const int2* __restrict__ pcnt, float* __restrict__ pbound,
    unsigned int* __restrict__ done, float* __restrict__ out) {
    int blk = blockIdx.x;            // [0, 512)
    int bc = blk >> 4;               // [0, 32)
    int xt = blk & 15;
    int b = bc >> 3, c = bc & 7;
    int tid = threadIdx.x;
    int ty = tid >> 2;
    int tx = tid & 3;
    int lane = tid & 63, wid = tid >> 6;

    __shared__ float h[2][H_DIM][LDS_PITCH];
    __shared__ int anyf[2];
    __shared__ double dred[256];
    __shared__ float wsum[4];
    __shared__ int sh_last;

    if (tid < 2) anyf[tid] = 0;
    __syncthreads();
    {
        int j0 = bc << 1;
        unsigned char f0 = rowflagP[(j0 << 8) + tid];
        unsigned char f1 = rowflagP[((j0 + 1) << 8) + tid];
        unsigned long long b0 = __ballot(f0 != 0);
        unsigned long long b1 = __ballot(f1 != 0);
        if (lane == 0) {
            if (b0) atomicOr(&anyf[0], 1);
            if (b1) atomicOr(&anyf[1], 1);
        }
    }

    // stage: fully-coalesced 16KB contiguous tile read; unpack+square into pitch-20 LDS
    {
        const unsigned int* base = d1t + ((size_t)bc * 16 + xt) * 4096;
#pragma unroll
        for (int k = 0; k < 4; ++k) {
            uint4 q = *(const uint4*)(base + (k << 10) + (tid << 2));
            int y = (tid >> 2) + (k << 6);
            int w0 = (tid & 3) << 2;
            float4 f0, f1;
            f0.x = (float)(q.x & 0xFFFFu); f1.x = (float)(q.x >> 16);
            f0.y = (float)(q.y & 0xFFFFu); f1.y = (float)(q.y >> 16);
            f0.z = (float)(q.z & 0xFFFFu); f1.z = (float)(q.z >> 16);
            f0.w = (float)(q.w & 0xFFFFu); f1.w = (float)(q.w >> 16);
            f0.x *= f0.x; f0.y *= f0.y; f0.z *= f0.z; f0.w *= f0.w;
            f1.x *= f1.x; f1.y *= f1.y; f1.z *= f1.z; f1.w *= f1.w;
            *(float4*)&h[0][y][w0] = f0;
            *(float4*)&h[1][y][w0] = f1;
        }
    }
    __syncthreads();

    int ybase = ty << 2;
    float m0[4][4], m1[4][4];

#pragma unroll
    for (int pol = 0; pol < 2; ++pol) {
        float gmax = 0.f;
#pragma unroll
        for (int iy = 0; iy < 4; ++iy) {
            float4 g = *(float4*)&h[pol][ybase + iy][tx << 2];
            gmax = fmaxf(gmax, fmaxf(fmaxf(g.x, g.y), fmaxf(g.z, g.w)));
        }
        int r = (int)sqrtf(gmax) + 1;
        int ylo = max(0, ybase - r);
        int yhi = min(H_DIM - 1, ybase + 3 + r);

        float (*mm)[4] = pol ? m1 : m0;
#pragma unroll
        for (int iy = 0; iy < 4; ++iy)
#pragma unroll
            for (int j = 0; j < 4; ++j) mm[iy][j] = 1e30f;

        for (int yp = ylo; yp <= yhi; ++yp) {
            float4 hv = *(float4*)&h[pol][yp][tx << 2];
            float dy0 = (float)(ybase - yp);
#pragma unroll
            for (int iy = 0; iy < 4; ++iy) {
                float dy = dy0 + (float)iy;
                mm[iy][0] = fminf(mm[iy][0], fmaf(dy, dy, hv.x));
                mm[iy][1] = fminf(mm[iy][1], fmaf(dy, dy, hv.y));
                mm[iy][2] = fminf(mm[iy][2], fmaf(dy, dy, hv.z));
                mm[iy][3] = fminf(mm[iy][3], fmaf(dy, dy, hv.w));
            }
        }
    }

    bool has_pos = anyf[0] != 0;
    bool has_neg = anyf[1] != 0;

    float lsum = 0.f;
    size_t pixbase = (size_t)b * HW;
    size_t xbase = ((size_t)b * C_DIM + c) * HW;
    int x0 = (xt << 4) + (tx << 2);
#pragma unroll
    for (int iy = 0; iy < 4; ++iy) {
        int y = ybase + iy;
        size_t rowoff = (size_t)y * W_DIM + x0;
        float4 xv = *(const float4*)(x + xbase + rowoff);
        float4 lv = *(const float4*)(lse + pixbase + rowoff);
        int4 tv = *(const int4*)(tgt + pixbase + rowoff);
#pragma unroll
        for (int j = 0; j < 4; ++j) {
            float dout = sqrtf(m0[iy][j]);
            float din  = sqrtf(m1[iy][j]);
            float sgn = has_pos ? (has_neg ? (dout - din) : dout) : 0.f;
            float xs = (j == 0) ? xv.x : (j == 1) ? xv.y : (j == 2) ? xv.z : xv.w;
            float ls = (j == 0) ? lv.x : (j == 1) ? lv.y : (j == 2) ? lv.z : lv.w;
            int tt   = (j == 0) ? tv.x : (j == 1) ? tv.y : (j == 2) ? tv.z : tv.w;
            bool vb = (tt >= 0) && (tt < C_DIM);
            float prob = __expf(xs - ls);
            lsum += vb ? prob * sgn : 0.f;
        }
    }

    float r2 = wave_reduce_f(lsum);
    if (lane == 0) wsum[wid] = r2;
    __syncthreads();
    if (tid == 0) {
        pbound[blk] = (wsum[0] + wsum[1]) + (wsum[2] + wsum[3]);
        __threadfence();
        unsigned int o = atomicAdd(done, 1u);
        sh_last = (o == 511u) ? 1 : 0;
    }
    __syncthreads();
    if (!sh_last) return;

    // ---- last block: final combine ----
    __threadfence();
    double s_ce = 0, s_in = 0, s_bd = 0, c_d = 0, c_b = 0;
    for (int k = tid; k < 1024; k += 256) {
        s_ce += (double)pce[k]; s_in += (double)pinter[k];
        int2 cc = pcnt[k]; c_d += (double)cc.x; c_b += (double)cc.y;
    }
    for (int k = tid; k < 512; k += 256) s_bd += (double)pbound[k];

    double sums[4]; double vin[4] = {s_ce, s_in, s_bd, c_d * 4194304.0 + c_b};
    for (int q = 0; q < 4; ++q) {
        dred[tid] = vin[q];
        __syncthreads();
        for (int s2 = 128; s2; s2 >>= 1) { if (tid < s2) dred[tid] += dred[tid + s2]; __syncthreads(); }
        sums[q] = dred[0];
        __syncthreads();
    }
    if (tid == 0) {
        double packed = sums[3];
        double cd = floor(packed / 4194304.0 + 1e-9);
        double cb = packed - cd * 4194304.0;
        double ce = sums[0] / (double)NPIX;
        double inter = sums[1];
        double card = cd + cb;
        double dice = 1.0 - (2.0 * inter + 1e-6) / (card + 1e-6);
        double dice_total = 0.1 * ce + 0.9 * dice;
        double bound = sums[2] / (cb + 1e-8);
        out[0] = (float)(0.1 * ce + 0.8 * dice_total + 0.1 * bound);
    }
}

extern "C" void kernel_launch(void* const* d_in, const int* in_sizes, int n_in,
                              void* d_out, int out_size, void* d_ws, size_t ws_size,
                              hipStream_t stream) {
    const float* x = (const float*)d_in[0];
    const int* tgt = (const int*)d_in[1];
    float* out = (float*)d_out;

    char* ws = (char*)d_ws;
    float* pce    = (float*)(ws + 0);
    float* pinter = (float*)(ws + 4096);
    int2*  pcnt   = (int2*)(ws + 8192);
    float* pbound = (float*)(ws + 16384);
    unsigned int* done = (unsigned int*)(ws + 18432);
    unsigned char* rowflagP = (unsigned char*)(ws + 20480);
    float* lse    = (float*)(ws + 65536);
    unsigned int* d1t = (unsigned int*)(ws + (size_t)(2u << 20));

    k_row<<<1024, 256, 0, stream>>>(x, tgt, lse, pce, pinter, pcnt, rowflagP, d1t, done);
    k_cols_fin<<<512, 256, 0, stream>>>(d1t, x, lse, tgt, rowflagP,
                                        pce, pinter, pcnt, pbound, done, out);
}

// Round 7
// 50.332 us; speedup vs baseline: 4.6139x; 1.0182x over previous
//
#include <hip/hip_runtime.h>
#include <math.h>

// Dims: B=4, C=8, H=W=256
#define B_DIM 4
#define C_DIM 8
#define H_DIM 256
#define W_DIM 256
#define HW 65536
#define NPIX 262144

// ws layout (no zero-init required; every slot written every call):
// [0,     4096)   float pce[1024]
// [4096,  8192)   float pinter[1024]
// [8192, 16384)   int2  pcnt[1024]
// [16384,18432)   float pbound[512]
// [18432,18436)   uint  done            (zeroed by k_row block 0 each call)
// [20480,36864)   uchar rowflagP[64*256]
// [65536,+1MB)    float lse[NPIX]
// [2MB,  +8MB)    uint  d1t[32][16][256][16]  tiled: [bc][xt][y][word]; word = d1_pol0 | d1_pol1<<16

__device__ __forceinline__ float wave_reduce_f(float v) {
#pragma unroll
    for (int off = 32; off; off >>= 1) v += __shfl_xor(v, off, 64);
    return v;
}

// ------------- Kernel 1: fused softmax stats + horizontal EDT for one (b,y) row -------------
__global__ void __launch_bounds__(256) k_row(
    const float* __restrict__ x, const int* __restrict__ tgt,
    float* __restrict__ lse_out, float* __restrict__ pce, float* __restrict__ pinter,
    int2* __restrict__ pcnt, unsigned char* __restrict__ rowflagP,
    unsigned int* __restrict__ d1t, unsigned int* __restrict__ done) {
    int bi = blockIdx.x;                 // [0,1024): b*256 + y
    int b = bi >> 8, y = bi & 255;
    int i = threadIdx.x;                 // column
    int lane = i & 63, wid = i >> 6;
    size_t rowbase = (size_t)b * HW + (size_t)y * W_DIM;

    if (bi == 0 && i == 0) *done = 0u;   // stream-ordered before kernel 2

    // ---- softmax / CE / Dice stats ----
    const float* xb = x + (size_t)b * C_DIM * HW + (size_t)y * W_DIM + i;
    float v[C_DIM];
    float m = -1e30f;
#pragma unroll
    for (int c = 0; c < C_DIM; ++c) { v[c] = xb[(size_t)c * HW]; m = fmaxf(m, v[c]); }
    float s = 0.f;
#pragma unroll
    for (int c = 0; c < C_DIM; ++c) s += __expf(v[c] - m);
    float lse = m + __logf(s);
    lse_out[rowbase + i] = lse;

    int t = tgt[rowbase + i];
    bool valid_d = (t >= 0);
    bool valid_b = valid_d && (t < C_DIM);
    int tc = valid_b ? t : 0;
    float vt = v[0];
#pragma unroll
    for (int c = 1; c < C_DIM; ++c) vt = (tc == c) ? v[c] : vt;

    float ce = lse - vt;
    float inter = valid_b ? __expf(vt - m) * (1.0f / s) : 0.f;

    __shared__ float ws_ce[4], ws_in[4];
    __shared__ int ws_cd[4], ws_cb[4];
    float r_ce = wave_reduce_f(ce);
    float r_in = wave_reduce_f(inter);
    unsigned long long md = __ballot(valid_d);
    unsigned long long mbv = __ballot(valid_b);
    if (lane == 0) {
        ws_ce[wid] = r_ce; ws_in[wid] = r_in;
        ws_cd[wid] = __popcll(md); ws_cb[wid] = __popcll(mbv);
    }

    // ---- row EDT via ballot masks ----
    __shared__ unsigned long long wmask[C_DIM][4];
#pragma unroll
    for (int c = 0; c < C_DIM; ++c) {
        unsigned long long mc = __ballot(valid_b && (t == c));
        if (lane == 0) wmask[c][wid] = mc;
    }
    __syncthreads();

    if (i == 0) {
        pce[bi] = (ws_ce[0] + ws_ce[1]) + (ws_ce[2] + ws_ce[3]);
        pinter[bi] = (ws_in[0] + ws_in[1]) + (ws_in[2] + ws_in[3]);
        pcnt[bi] = make_int2((ws_cd[0] + ws_cd[1]) + (ws_cd[2] + ws_cd[3]),
                             (ws_cb[0] + ws_cb[1]) + (ws_cb[2] + ws_cb[3]));
    }
    if (i < 16) {   // per-(c,pol) row seed flags
        int c = i >> 1, pol = i & 1;
        unsigned long long o = wmask[c][0] | wmask[c][1] | wmask[c][2] | wmask[c][3];
        unsigned long long a = wmask[c][0] & wmask[c][1] & wmask[c][2] & wmask[c][3];
        bool any = pol ? (a != ~0ull) : (o != 0ull);
        int j = ((b * C_DIM + c) << 1) + pol;
        rowflagP[(j << 8) + y] = any ? 1 : 0;
    }

    unsigned long long lm_le = (~0ull) >> (63 - lane);
    unsigned long long lm_ge = (~0ull) << lane;

#pragma unroll 1
    for (int c = 0; c < C_DIM; ++c) {
        unsigned long long m0 = wmask[c][wid];
        int d1v[2];
#pragma unroll
        for (int pol = 0; pol < 2; ++pol) {
            unsigned long long mk = pol ? ~m0 : m0;
            unsigned long long mle = mk & lm_le;
            unsigned long long mge = mk & lm_ge;
            int last, next;
            if (mle) last = (wid << 6) + 63 - __builtin_clzll(mle);
            else {
                last = -1000;
                for (int w = wid - 1; w >= 0; --w) {
                    unsigned long long mw = pol ? ~wmask[c][w] : wmask[c][w];
                    if (mw) { last = (w << 6) + 63 - __builtin_clzll(mw); break; }
                }
            }
            if (mge) next = (wid << 6) + __builtin_ctzll(mge);
            else {
                next = 100000;
                for (int w = wid + 1; w < 4; ++w) {
                    unsigned long long mw = pol ? ~wmask[c][w] : wmask[c][w];
                    if (mw) { next = (w << 6) + __builtin_ctzll(mw); break; }
                }
            }
            d1v[pol] = min(min(i - last, next - i), 512);
        }
        int bc = b * C_DIM + c;
        d1t[(((size_t)bc * 16 + (i >> 4)) * 256 + y) * 16 + (i & 15)] =
            (unsigned int)d1v[0] | ((unsigned int)d1v[1] << 16);
    }
}

// ------------- Kernel 2: windowed exact vertical envelope + boundary sum + finalize -------------
// POL_BODY: statically-named accumulators (NO pointer-select — keeps them in VGPRs).
#define LDS_PITCH 20
#define POL_BODY(MP, HP)                                                        \
    {                                                                           \
        float gmax = 0.f;                                                       \
        _Pragma("unroll")                                                       \
        for (int iy = 0; iy < 4; ++iy) {                                        \
            float4 g = *(float4*)&HP[ybase + iy][tx << 2];                      \
            gmax = fmaxf(gmax, fmaxf(fmaxf(g.x, g.y), fmaxf(g.z, g.w)));        \
        }                                                                       \
        int r = (int)sqrtf(gmax) + 1;                                           \
        int ylo = max(0, ybase - r);                                            \
        int yhi = min(H_DIM - 1, ybase + 3 + r);                                \
        _Pragma("unroll")                                                       \
        for (int iy = 0; iy < 4; ++iy)                                          \
            _Pragma("unroll")                                                   \
            for (int j = 0; j < 4; ++j) MP[iy][j] = 1e30f;                      \
        for (int yp = ylo; yp <= yhi; ++yp) {                                   \
            float4 hv = *(float4*)&HP[yp][tx << 2];                             \
            float dy0 = (float)(ybase - yp);                                    \
            _Pragma("unroll")                                                   \
            for (int iy = 0; iy < 4; ++iy) {                                    \
                float dy = dy0 + (float)iy;                                     \
                MP[iy][0] = fminf(MP[iy][0], fmaf(dy, dy, hv.x));               \
                MP[iy][1] = fminf(MP[iy][1], fmaf(dy, dy, hv.y));               \
                MP[iy][2] = fminf(MP[iy][2], fmaf(dy, dy, hv.z));               \
                MP[iy][3] = fminf(MP[iy][3], fmaf(dy, dy, hv.w));               \
            }                                                                   \
        }                                                                       \
    }

__global__ void __launch_bounds__(256) k_cols_fin(
    const unsigned int* __restrict__ d1t, const float* __restrict__ x,
    const float* __restrict__ lse, const int* __restrict__ tgt,
    const unsigned char* __restrict__ rowflagP,
    const float* __restrict__ pce, const float* __restrict__ pinter,
    const int2* __restrict__ pcnt, float* __restrict__ pbound,
    unsigned int* __restrict__ done, float* __restrict__ out) {
    int blk = blockIdx.x;            // [0, 512)
    int bc = blk >> 4;               // [0, 32)
    int xt = blk & 15;
    int b = bc >> 3, c = bc & 7;
    int tid = threadIdx.x;
    int ty = tid >> 2;
    int tx = tid & 3;
    int lane = tid & 63, wid = tid >> 6;

    __shared__ float h0s[H_DIM][LDS_PITCH];
    __shared__ float h1s[H_DIM][LDS_PITCH];
    __shared__ int anyf[2];
    __shared__ double dred[256];
    __shared__ float wsum[4];
    __shared__ int sh_last;

    if (tid < 2) anyf[tid] = 0;
    __syncthreads();
    {
        int j0 = bc << 1;
        unsigned char f0 = rowflagP[(j0 << 8) + tid];
        unsigned char f1 = rowflagP[((j0 + 1) << 8) + tid];
        unsigned long long b0 = __ballot(f0 != 0);
        unsigned long long b1 = __ballot(f1 != 0);
        if (lane == 0) {
            if (b0) atomicOr(&anyf[0], 1);
            if (b1) atomicOr(&anyf[1], 1);
        }
    }

    // stage: fully-coalesced 16KB contiguous tile read; unpack+square into pitch-20 LDS
    {
        const unsigned int* base = d1t + ((size_t)bc * 16 + xt) * 4096;
#pragma unroll
        for (int k = 0; k < 4; ++k) {
            uint4 q = *(const uint4*)(base + (k << 10) + (tid << 2));
            int y = (tid >> 2) + (k << 6);
            int w0 = (tid & 3) << 2;
            float4 f0, f1;
            f0.x = (float)(q.x & 0xFFFFu); f1.x = (float)(q.x >> 16);
            f0.y = (float)(q.y & 0xFFFFu); f1.y = (float)(q.y >> 16);
            f0.z = (float)(q.z & 0xFFFFu); f1.z = (float)(q.z >> 16);
            f0.w = (float)(q.w & 0xFFFFu); f1.w = (float)(q.w >> 16);
            f0.x *= f0.x; f0.y *= f0.y; f0.z *= f0.z; f0.w *= f0.w;
            f1.x *= f1.x; f1.y *= f1.y; f1.z *= f1.z; f1.w *= f1.w;
            *(float4*)&h0s[y][w0] = f0;
            *(float4*)&h1s[y][w0] = f1;
        }
    }
    __syncthreads();

    int ybase = ty << 2;
    float m0[4][4], m1[4][4];
    POL_BODY(m0, h0s)
    POL_BODY(m1, h1s)

    bool has_pos = anyf[0] != 0;
    bool has_neg = anyf[1] != 0;

    float lsum = 0.f;
    size_t pixbase = (size_t)b * HW;
    size_t xbase = ((size_t)b * C_DIM + c) * HW;
    int x0 = (xt << 4) + (tx << 2);
#pragma unroll
    for (int iy = 0; iy < 4; ++iy) {
        int y = ybase + iy;
        size_t rowoff = (size_t)y * W_DIM + x0;
        float4 xv = *(const float4*)(x + xbase + rowoff);
        float4 lv = *(const float4*)(lse + pixbase + rowoff);
        int4 tv = *(const int4*)(tgt + pixbase + rowoff);
#pragma unroll
        for (int j = 0; j < 4; ++j) {
            float dout = sqrtf((j == 0) ? m0[iy][0] : (j == 1) ? m0[iy][1] : (j == 2) ? m0[iy][2] : m0[iy][3]);
            float din  = sqrtf((j == 0) ? m1[iy][0] : (j == 1) ? m1[iy][1] : (j == 2) ? m1[iy][2] : m1[iy][3]);
            float sgn = has_pos ? (has_neg ? (dout - din) : dout) : 0.f;
            float xs = (j == 0) ? xv.x : (j == 1) ? xv.y : (j == 2) ? xv.z : xv.w;
            float ls = (j == 0) ? lv.x : (j == 1) ? lv.y : (j == 2) ? lv.z : lv.w;
            int tt   = (j == 0) ? tv.x : (j == 1) ? tv.y : (j == 2) ? tv.z : tv.w;
            bool vb = (tt >= 0) && (tt < C_DIM);
            float prob = __expf(xs - ls);
            lsum += vb ? prob * sgn : 0.f;
        }
    }

    float r2 = wave_reduce_f(lsum);
    if (lane == 0) wsum[wid] = r2;
    __syncthreads();
    if (tid == 0) {
        pbound[blk] = (wsum[0] + wsum[1]) + (wsum[2] + wsum[3]);
        __threadfence();
        unsigned int o = atomicAdd(done, 1u);
        sh_last = (o == 511u) ? 1 : 0;
    }
    __syncthreads();
    if (!sh_last) return;

    // ---- last block: final combine ----
    __threadfence();
    double s_ce = 0, s_in = 0, s_bd = 0, c_d = 0, c_b = 0;
    for (int k = tid; k < 1024; k += 256) {
        s_ce += (double)pce[k]; s_in += (double)pinter[k];
        int2 cc = pcnt[k]; c_d += (double)cc.x; c_b += (double)cc.y;
    }
    for (int k = tid; k < 512; k += 256) s_bd += (double)pbound[k];

    double sums[4]; double vin[4] = {s_ce, s_in, s_bd, c_d * 4194304.0 + c_b};
    for (int q = 0; q < 4; ++q) {
        dred[tid] = vin[q];
        __syncthreads();
        for (int s2 = 128; s2; s2 >>= 1) { if (tid < s2) dred[tid] += dred[tid + s2]; __syncthreads(); }
        sums[q] = dred[0];
        __syncthreads();
    }
    if (tid == 0) {
        double packed = sums[3];
        double cd = floor(packed / 4194304.0 + 1e-9);
        double cb = packed - cd * 4194304.0;
        double ce = sums[0] / (double)NPIX;
        double inter = sums[1];
        double card = cd + cb;
        double dice = 1.0 - (2.0 * inter + 1e-6) / (card + 1e-6);
        double dice_total = 0.1 * ce + 0.9 * dice;
        double bound = sums[2] / (cb + 1e-8);
        out[0] = (float)(0.1 * ce + 0.8 * dice_total + 0.1 * bound);
    }
}

extern "C" void kernel_launch(void* const* d_in, const int* in_sizes, int n_in,
                              void* d_out, int out_size, void* d_ws, size_t ws_size,
                              hipStream_t stream) {
    const float* x = (const float*)d_in[0];
    const int* tgt = (const int*)d_in[1];
    float* out = (float*)d_out;

    char* ws = (char*)d_ws;
    float* pce    = (float*)(ws + 0);
    float* pinter = (float*)(ws + 4096);
    int2*  pcnt   = (int2*)(ws + 8192);
    float* pbound = (float*)(ws + 16384);
    unsigned int* done = (unsigned int*)(ws + 18432);
    unsigned char* rowflagP = (unsigned char*)(ws + 20480);
    float* lse    = (float*)(ws + 65536);
    unsigned int* d1t = (unsigned int*)(ws + (size_t)(2u << 20));

    k_row<<<1024, 256, 0, stream>>>(x, tgt, lse, pce, pinter, pcnt, rowflagP, d1t, done);
    k_cols_fin<<<512, 256, 0, stream>>>(d1t, x, lse, tgt, rowflagP,
                                        pce, pinter, pcnt, pbound, done, out);
}